// Round 7
// baseline (447.319 us; speedup 1.0000x reference)
//
#include <hip/hip_runtime.h>
#include <hip/hip_fp16.h>

#define N_USERS 100000
#define N_ITEMS 50000
#define N_NODES 150000
#define DIM 64
#define NNZ 4000000
#define BATCH 4096

#define NBUCK 586          // ceil(150000/256) buckets of 256 nodes
#define CAP   7680         // bucket capacity: mean 6827, sigma 82.5 -> +10.3 sigma
#define NB_C  512          // coarse blocks (2/CU -> ~50% occupancy)

typedef __half f16;

__device__ __forceinline__ float h2f(f16 h) { return __half2float(h); }

// ---------------- gticket init: gticket[k] = k*CAP ---------------------------
__global__ void initt_k(int* __restrict__ gticket) {
    int i = blockIdx.x * blockDim.x + threadIdx.x;
    if (i < NBUCK) gticket[i] = i * CAP;
}

// ---------------- coarse: bucket edges by dst>>8 via LDS hist + block tickets
__global__ __launch_bounds__(512) void coarse_k(
        const int* __restrict__ src, const int* __restrict__ dst,
        const float* __restrict__ val, int* __restrict__ gticket,
        int2* __restrict__ ev, unsigned char* __restrict__ dlo) {
    __shared__ int hist[NBUCK];
    __shared__ int base[NBUCK];
    __shared__ int tick[NBUCK];
    int t  = threadIdx.x;
    int b  = blockIdx.x;
    const int q = NNZ / NB_C, r = NNZ % NB_C;
    int lo = b * q + (b < r ? b : r);
    int hi = lo + q + (b < r ? 1 : 0);
    for (int i = t; i < NBUCK; i += blockDim.x) hist[i] = 0;
    __syncthreads();
    for (int e = lo + t; e < hi; e += blockDim.x)
        atomicAdd(&hist[dst[e] >> 8], 1);
    __syncthreads();
    for (int i = t; i < NBUCK; i += blockDim.x) {
        base[i] = atomicAdd(&gticket[i], hist[i]);   // one agent atomic per (block,bucket)
        tick[i] = 0;
    }
    __syncthreads();
    for (int e = lo + t; e < hi; e += blockDim.x) {
        int d  = dst[e];
        int bk = d >> 8;
        int p  = base[bk] + atomicAdd(&tick[bk], 1); // LDS ticket
        ev[p]  = make_int2(src[e], __float_as_int(val[e]));
        dlo[p] = (unsigned char)(d & 255);
    }
}

// ---------------- scanC: bucket bases from final tickets ---------------------
__global__ void scanC_k(const int* __restrict__ gticket, int* __restrict__ bktbase) {
    __shared__ int sh[1024];
    int tid = threadIdx.x;
    int v = (tid < NBUCK) ? (gticket[tid] - tid * CAP) : 0;
    sh[tid] = v;
    __syncthreads();
    for (int off = 1; off < 1024; off <<= 1) {
        int t = (tid >= off) ? sh[tid - off] : 0;
        __syncthreads();
        sh[tid] += t;
        __syncthreads();
    }
    if (tid < NBUCK) bktbase[tid] = sh[tid] - v;   // exclusive
}

// ---------------- fine: per-bucket counting sort fully in LDS ----------------
__global__ void fine_k(const int* __restrict__ gticket, const int* __restrict__ bktbase,
                       const int2* __restrict__ ev, const unsigned char* __restrict__ dlo,
                       int2* __restrict__ sorted, int* __restrict__ row) {
    __shared__ int hist[256];
    __shared__ int sh[256];
    int k = blockIdx.x, t = threadIdx.x;
    hist[t] = 0;
    __syncthreads();
    int cnt = gticket[k] - k * CAP;
    int s0  = k * CAP;
    for (int i = t; i < cnt; i += 256)
        atomicAdd(&hist[dlo[s0 + i]], 1);
    __syncthreads();
    int v = hist[t];
    sh[t] = v;
    __syncthreads();
    for (int off = 1; off < 256; off <<= 1) {
        int tmp = (t >= off) ? sh[t - off] : 0;
        __syncthreads();
        sh[t] += tmp;
        __syncthreads();
    }
    int excl    = sh[t] - v;
    int rowbase = bktbase[k];
    int node    = (k << 8) + t;
    if (node < N_NODES) row[node] = rowbase + excl;
    if (k == 0 && t == 0) row[N_NODES] = NNZ;
    hist[t] = excl;                 // re-seed as ticket
    __syncthreads();
    for (int i = t; i < cnt; i += 256) {
        int p = atomicAdd(&hist[dlo[s0 + i]], 1);   // LDS ticket = local pos
        sorted[rowbase + p] = ev[s0 + i];
    }
}

// ---------------- conv: concat embeddings into X0 (fp16) ---------------------
__global__ void conv_k(const float4* __restrict__ ue, const float4* __restrict__ ie,
                       ushort4* __restrict__ X0) {
    int i = blockIdx.x * blockDim.x + threadIdx.x;
    const int total  = N_NODES * DIM / 4;
    const int ubound = N_USERS * DIM / 4;
    if (i >= total) return;
    float4 v = (i < ubound) ? ue[i] : ie[i - ubound];
    f16 a = __float2half(v.x), b = __float2half(v.y);
    f16 c = __float2half(v.z), d = __float2half(v.w);
    ushort4 o;
    o.x = *reinterpret_cast<ushort*>(&a);
    o.y = *reinterpret_cast<ushort*>(&b);
    o.z = *reinterpret_cast<ushort*>(&c);
    o.w = *reinterpret_cast<ushort*>(&d);
    X0[i] = o;
}

// ---------------- gather SpMM (fp16 in/out): Y[d] = sum val*X[src] ----------
// unroll 8: 8 independent X-row loads in flight per batch
__global__ void gather16_k(const int* __restrict__ row, const int2* __restrict__ se,
                           const f16* __restrict__ X, f16* __restrict__ Y) {
    int wid  = (blockIdx.x * blockDim.x + threadIdx.x) >> 6;   // node
    int lane = threadIdx.x & 63;                               // dim
    if (wid >= N_NODES) return;
    int beg = row[wid], end = row[wid + 1];
    float acc = 0.f;
    for (int base = beg; base < end; base += 64) {
        int rem = end - base;
        int n = rem < 64 ? rem : 64;
        int2 evv = make_int2(0, 0);
        if (lane < n) evv = se[base + lane];
        int n8 = (n + 7) & ~7;
        for (int j = 0; j < n8; j += 8) {
            float xv[8], vv[8];
            #pragma unroll
            for (int k = 0; k < 8; ++k) {
                int s = __shfl(evv.x, j + k, 64);
                vv[k] = __int_as_float(__shfl(evv.y, j + k, 64));
                xv[k] = h2f(X[(s << 6) + lane]);   // padded lanes: v=0, s=0 (safe)
            }
            #pragma unroll
            for (int k = 0; k < 8; ++k) acc += vv[k] * xv[k];
        }
    }
    Y[(wid << 6) + lane] = __float2half(acc);
}

// ---------------- final: acc = (e0+x1+x2+x3)/4 for gathered rows, dot, sigmoid
__global__ void final_k(const int* __restrict__ users, const int* __restrict__ items,
                        const float* __restrict__ ue, const float* __restrict__ ie,
                        const f16* __restrict__ X1, const f16* __restrict__ X2,
                        const f16* __restrict__ X3, float* __restrict__ out) {
    int b    = blockIdx.x * (blockDim.x / 64) + (threadIdx.x / 64);
    int lane = threadIdx.x & 63;
    if (b >= BATCH) return;
    int u  = users[b];
    int it = items[b];
    int uo = (u << 6) + lane;
    int io = ((N_USERS + it) << 6) + lane;
    float au = ue[uo]               + h2f(X1[uo]) + h2f(X2[uo]) + h2f(X3[uo]);
    float ai = ie[(it << 6) + lane] + h2f(X1[io]) + h2f(X2[io]) + h2f(X3[io]);
    float p = au * ai * (1.0f / 16.0f);
    #pragma unroll
    for (int off = 32; off; off >>= 1) p += __shfl_down(p, off, 64);
    if (lane == 0) out[b] = 1.0f / (1.0f + __expf(-p));
}

extern "C" void kernel_launch(void* const* d_in, const int* in_sizes, int n_in,
                              void* d_out, int out_size, void* d_ws, size_t ws_size,
                              hipStream_t stream) {
    const int*   users = (const int*)  d_in[0];
    const int*   items = (const int*)  d_in[1];
    const int*   esrc  = (const int*)  d_in[2];
    const int*   edst  = (const int*)  d_in[3];
    const float* eval  = (const float*)d_in[4];
    const float* uemb  = (const float*)d_in[5];
    const float* iemb  = (const float*)d_in[6];
    float*       out   = (float*)      d_out;

    const size_t XB = (size_t)N_NODES * DIM * sizeof(f16);         // 19.2 MB
    char* ws = (char*)d_ws;
    f16*  X0     = (f16*) (ws);
    f16*  X1     = (f16*) (ws + XB);
    f16*  X2     = (f16*) (ws + 2 * XB);
    f16*  X3     = (f16*) (ws + 3 * XB);
    int2* sorted = (int2*)(ws + 4 * XB);                           // 32 MB
    char* p      = ws + 4 * XB + (size_t)NNZ * sizeof(int2);
    int*  row     = (int*)(p);                 p += ((size_t)(N_NODES + 1) * 4 + 255) & ~255UL;
    int*  gticket = (int*)(p);                 p += (NBUCK * 4 + 255) & ~255UL;
    int*  bktbase = (int*)(p);
    // coarse staging aliases X0..X3 (dead until conv_k / gathers)
    int2*          cev  = (int2*)(ws);                             // 36.0 MB (over X0+X1)
    unsigned char* cdlo = (unsigned char*)(ws + 2 * XB);           // 4.5 MB (over X2)

    // ---- CSR build: LDS counting sort, no fabric atomics on hot path ----
    initt_k<<<(NBUCK + 255) / 256, 256, 0, stream>>>(gticket);
    coarse_k<<<NB_C, 512, 0, stream>>>(esrc, edst, eval, gticket, cev, cdlo);
    scanC_k<<<1, 1024, 0, stream>>>(gticket, bktbase);
    fine_k<<<NBUCK, 256, 0, stream>>>(gticket, bktbase, cev, cdlo, sorted, row);

    // ---- X0 = concat(uemb, iemb) in fp16 (coarse staging now dead) ----
    conv_k<<<(N_NODES * DIM / 4 + 255) / 256, 256, 0, stream>>>(
        (const float4*)uemb, (const float4*)iemb, (ushort4*)X0);

    // ---- 3 gather layers ----
    const int gthreads = N_NODES * 64;
    gather16_k<<<(gthreads + 255) / 256, 256, 0, stream>>>(row, sorted, X0, X1);
    gather16_k<<<(gthreads + 255) / 256, 256, 0, stream>>>(row, sorted, X1, X2);
    gather16_k<<<(gthreads + 255) / 256, 256, 0, stream>>>(row, sorted, X2, X3);

    final_k<<<(BATCH * 64 + 255) / 256, 256, 0, stream>>>(users, items, uemb, iemb,
                                                          X1, X2, X3, out);
}

// Round 8
// 308.025 us; speedup vs baseline: 1.4522x; 1.4522x over previous
//
#include <hip/hip_runtime.h>
#include <hip/hip_fp16.h>

#define N_USERS 100000
#define N_ITEMS 50000
#define N_NODES 150000
#define DIM 64
#define NNZ 4000000
#define BATCH 4096

#define NBUCK 586          // ceil(150000/256) buckets of 256 nodes
#define CAP   7680         // bucket capacity: mean 6827, sigma 82.5 -> +10.3 sigma
#define NB_C  256          // coarse blocks (512 was worse: cursor thrash)
#define CHUNK (NNZ / NB_C) // 15625

typedef __half f16;

__device__ __forceinline__ float h2f(f16 h) { return __half2float(h); }

// record: .x = src | (d&255)<<18   .y = val bits
// ---------------- gticket init: gticket[k] = k*CAP ---------------------------
__global__ void initt_k(int* __restrict__ gticket) {
    int i = blockIdx.x * blockDim.x + threadIdx.x;
    if (i < NBUCK) gticket[i] = i * CAP;
}

// ---------------- coarse: bucket edges by dst>>8, single 8B packed store -----
__global__ __launch_bounds__(512) void coarse_k(
        const int* __restrict__ src, const int* __restrict__ dst,
        const float* __restrict__ val, int* __restrict__ gticket,
        int2* __restrict__ ev) {
    __shared__ int hist[NBUCK];
    __shared__ int base[NBUCK];
    __shared__ int tick[NBUCK];
    int t  = threadIdx.x;
    int lo = blockIdx.x * CHUNK;
    int hi = lo + CHUNK;           // NNZ divisible by NB_C
    for (int i = t; i < NBUCK; i += blockDim.x) hist[i] = 0;
    __syncthreads();
    for (int e = lo + t; e < hi; e += blockDim.x)
        atomicAdd(&hist[dst[e] >> 8], 1);
    __syncthreads();
    for (int i = t; i < NBUCK; i += blockDim.x) {
        base[i] = atomicAdd(&gticket[i], hist[i]);   // one agent atomic per (block,bucket)
        tick[i] = 0;
    }
    __syncthreads();
    for (int e = lo + t; e < hi; e += blockDim.x) {
        int d  = dst[e];
        int bk = d >> 8;
        int p  = base[bk] + atomicAdd(&tick[bk], 1); // LDS ticket
        ev[p]  = make_int2(src[e] | ((d & 255) << 18), __float_as_int(val[e]));
    }
}

// ---------------- scanC: bucket bases from final tickets ---------------------
__global__ void scanC_k(const int* __restrict__ gticket, int* __restrict__ bktbase) {
    __shared__ int sh[1024];
    int tid = threadIdx.x;
    int v = (tid < NBUCK) ? (gticket[tid] - tid * CAP) : 0;
    sh[tid] = v;
    __syncthreads();
    for (int off = 1; off < 1024; off <<= 1) {
        int t = (tid >= off) ? sh[tid - off] : 0;
        __syncthreads();
        sh[tid] += t;
        __syncthreads();
    }
    if (tid < NBUCK) bktbase[tid] = sh[tid] - v;   // exclusive
}

// ---------------- fine: per-bucket counting sort fully in LDS ----------------
__global__ void fine_k(const int* __restrict__ gticket, const int* __restrict__ bktbase,
                       const int2* __restrict__ ev,
                       int2* __restrict__ sorted, int* __restrict__ row) {
    __shared__ int hist[256];
    __shared__ int sh[256];
    int k = blockIdx.x, t = threadIdx.x;
    hist[t] = 0;
    __syncthreads();
    int cnt = gticket[k] - k * CAP;
    int s0  = k * CAP;
    for (int i = t; i < cnt; i += 256)
        atomicAdd(&hist[(ev[s0 + i].x >> 18) & 255], 1);
    __syncthreads();
    int v = hist[t];
    sh[t] = v;
    __syncthreads();
    for (int off = 1; off < 256; off <<= 1) {
        int tmp = (t >= off) ? sh[t - off] : 0;
        __syncthreads();
        sh[t] += tmp;
        __syncthreads();
    }
    int excl    = sh[t] - v;
    int rowbase = bktbase[k];
    int node    = (k << 8) + t;
    if (node < N_NODES) row[node] = rowbase + excl;
    if (k == 0 && t == 0) row[N_NODES] = NNZ;
    hist[t] = excl;                 // re-seed as ticket
    __syncthreads();
    for (int i = t; i < cnt; i += 256) {
        int2 r = ev[s0 + i];
        int p  = atomicAdd(&hist[(r.x >> 18) & 255], 1);   // LDS ticket = local pos
        sorted[rowbase + p] = make_int2(r.x & 0x3FFFF, r.y);
    }
}

// ---------------- conv: concat embeddings into X0 (fp16) ---------------------
__global__ void conv_k(const float4* __restrict__ ue, const float4* __restrict__ ie,
                       ushort4* __restrict__ X0) {
    int i = blockIdx.x * blockDim.x + threadIdx.x;
    const int total  = N_NODES * DIM / 4;
    const int ubound = N_USERS * DIM / 4;
    if (i >= total) return;
    float4 v = (i < ubound) ? ue[i] : ie[i - ubound];
    f16 a = __float2half(v.x), b = __float2half(v.y);
    f16 c = __float2half(v.z), d = __float2half(v.w);
    ushort4 o;
    o.x = *reinterpret_cast<ushort*>(&a);
    o.y = *reinterpret_cast<ushort*>(&b);
    o.z = *reinterpret_cast<ushort*>(&c);
    o.w = *reinterpret_cast<ushort*>(&d);
    X0[i] = o;
}

// ---------------- gather SpMM (fp16 in/out): Y[d] = sum val*X[src] ----------
__global__ void gather16_k(const int* __restrict__ row, const int2* __restrict__ se,
                           const f16* __restrict__ X, f16* __restrict__ Y) {
    int wid  = (blockIdx.x * blockDim.x + threadIdx.x) >> 6;   // node
    int lane = threadIdx.x & 63;                               // dim
    if (wid >= N_NODES) return;
    int beg = row[wid], end = row[wid + 1];
    float acc = 0.f;
    for (int base = beg; base < end; base += 64) {
        int rem = end - base;
        int n = rem < 64 ? rem : 64;
        int2 evv = make_int2(0, 0);
        if (lane < n) evv = se[base + lane];
        int n8 = (n + 7) & ~7;
        for (int j = 0; j < n8; j += 8) {
            float xv[8], vv[8];
            #pragma unroll
            for (int k = 0; k < 8; ++k) {
                int s = __shfl(evv.x, j + k, 64);
                vv[k] = __int_as_float(__shfl(evv.y, j + k, 64));
                xv[k] = h2f(X[(s << 6) + lane]);   // padded lanes: v=0, s=0 (safe)
            }
            #pragma unroll
            for (int k = 0; k < 8; ++k) acc += vv[k] * xv[k];
        }
    }
    Y[(wid << 6) + lane] = __float2half(acc);
}

// ---------------- gather layer 3 for ONLY the batch's nodes ------------------
// slot s in [0,4096): user node users[s]; s in [4096,8192): item node
__global__ void gather3_k(const int* __restrict__ users, const int* __restrict__ items,
                          const int* __restrict__ row, const int2* __restrict__ se,
                          const f16* __restrict__ X, f16* __restrict__ X3p) {
    int s    = (blockIdx.x * blockDim.x + threadIdx.x) >> 6;   // slot
    int lane = threadIdx.x & 63;
    if (s >= 2 * BATCH) return;
    int wid = (s < BATCH) ? users[s] : (N_USERS + items[s - BATCH]);
    int beg = row[wid], end = row[wid + 1];
    float acc = 0.f;
    for (int base = beg; base < end; base += 64) {
        int rem = end - base;
        int n = rem < 64 ? rem : 64;
        int2 evv = make_int2(0, 0);
        if (lane < n) evv = se[base + lane];
        int n8 = (n + 7) & ~7;
        for (int j = 0; j < n8; j += 8) {
            float xv[8], vv[8];
            #pragma unroll
            for (int k = 0; k < 8; ++k) {
                int sr = __shfl(evv.x, j + k, 64);
                vv[k] = __int_as_float(__shfl(evv.y, j + k, 64));
                xv[k] = h2f(X[(sr << 6) + lane]);
            }
            #pragma unroll
            for (int k = 0; k < 8; ++k) acc += vv[k] * xv[k];
        }
    }
    X3p[(s << 6) + lane] = __float2half(acc);
}

// ---------------- final: acc = (e0+x1+x2+x3)/4 for gathered rows, dot, sigmoid
__global__ void final_k(const int* __restrict__ users, const int* __restrict__ items,
                        const float* __restrict__ ue, const float* __restrict__ ie,
                        const f16* __restrict__ X1, const f16* __restrict__ X2,
                        const f16* __restrict__ X3p, float* __restrict__ out) {
    int b    = blockIdx.x * (blockDim.x / 64) + (threadIdx.x / 64);
    int lane = threadIdx.x & 63;
    if (b >= BATCH) return;
    int u  = users[b];
    int it = items[b];
    int uo = (u << 6) + lane;
    int io = ((N_USERS + it) << 6) + lane;
    float au = ue[uo]               + h2f(X1[uo]) + h2f(X2[uo]) + h2f(X3p[(b << 6) + lane]);
    float ai = ie[(it << 6) + lane] + h2f(X1[io]) + h2f(X2[io]) + h2f(X3p[((b + BATCH) << 6) + lane]);
    float p = au * ai * (1.0f / 16.0f);
    #pragma unroll
    for (int off = 32; off; off >>= 1) p += __shfl_down(p, off, 64);
    if (lane == 0) out[b] = 1.0f / (1.0f + __expf(-p));
}

extern "C" void kernel_launch(void* const* d_in, const int* in_sizes, int n_in,
                              void* d_out, int out_size, void* d_ws, size_t ws_size,
                              hipStream_t stream) {
    const int*   users = (const int*)  d_in[0];
    const int*   items = (const int*)  d_in[1];
    const int*   esrc  = (const int*)  d_in[2];
    const int*   edst  = (const int*)  d_in[3];
    const float* eval  = (const float*)d_in[4];
    const float* uemb  = (const float*)d_in[5];
    const float* iemb  = (const float*)d_in[6];
    float*       out   = (float*)      d_out;

    const size_t XB = (size_t)N_NODES * DIM * sizeof(f16);         // 19.2 MB
    char* ws = (char*)d_ws;
    f16*  X0     = (f16*) (ws);
    f16*  X1     = (f16*) (ws + XB);
    f16*  X2     = (f16*) (ws + 2 * XB);
    f16*  X3p    = (f16*) (ws + 3 * XB);                           // 1 MB (2*BATCH rows)
    int2* sorted = (int2*)(ws + 3 * XB + ((size_t)2 * BATCH * DIM * 2 + 255 & ~255UL));
    char* p      = (char*)sorted + (size_t)NNZ * sizeof(int2);     // 32 MB
    int*  row     = (int*)(p);                 p += ((size_t)(N_NODES + 1) * 4 + 255) & ~255UL;
    int*  gticket = (int*)(p);                 p += (NBUCK * 4 + 255) & ~255UL;
    int*  bktbase = (int*)(p);
    // coarse staging aliases X0+X1 (dead until conv_k / gathers)
    int2* cev = (int2*)(ws);                                       // 32 MB

    // ---- CSR build: LDS counting sort, no fabric atomics on hot path ----
    initt_k<<<(NBUCK + 255) / 256, 256, 0, stream>>>(gticket);
    coarse_k<<<NB_C, 512, 0, stream>>>(esrc, edst, eval, gticket, cev);
    scanC_k<<<1, 1024, 0, stream>>>(gticket, bktbase);
    fine_k<<<NBUCK, 256, 0, stream>>>(gticket, bktbase, cev, sorted, row);

    // ---- X0 = concat(uemb, iemb) in fp16 (coarse staging now dead) ----
    conv_k<<<(N_NODES * DIM / 4 + 255) / 256, 256, 0, stream>>>(
        (const float4*)uemb, (const float4*)iemb, (ushort4*)X0);

    // ---- layers 1,2 full; layer 3 only for batch nodes ----
    const int gthreads = N_NODES * 64;
    gather16_k<<<(gthreads + 255) / 256, 256, 0, stream>>>(row, sorted, X0, X1);
    gather16_k<<<(gthreads + 255) / 256, 256, 0, stream>>>(row, sorted, X1, X2);
    gather3_k<<<(2 * BATCH * 64 + 255) / 256, 256, 0, stream>>>(users, items, row,
                                                                sorted, X2, X3p);

    final_k<<<(BATCH * 64 + 255) / 256, 256, 0, stream>>>(users, items, uemb, iemb,
                                                          X1, X2, X3p, out);
}

// Round 9
// 247.067 us; speedup vs baseline: 1.8105x; 1.2467x over previous
//
#include <hip/hip_runtime.h>
#include <hip/hip_fp16.h>

#define N_USERS 100000
#define N_ITEMS 50000
#define N_NODES 150000
#define DIM 64
#define NNZ 4000000
#define BATCH 4096

#define NBUCK 586          // ceil(150000/256) buckets of 256 nodes
#define CAP   7680         // bucket capacity: mean 6827, sigma 82.5 -> +10.3 sigma
#define NB_C  256          // coarse blocks (512 was worse: cursor thrash)
#define CHUNK (NNZ / NB_C) // 15625

typedef __half f16;

__device__ __forceinline__ float h2f(f16 h) { return __half2float(h); }

// record: .x = src | (d&255)<<18   .y = val bits
// ---------------- gticket init: gticket[k] = k*CAP ---------------------------
__global__ void initt_k(int* __restrict__ gticket) {
    int i = blockIdx.x * blockDim.x + threadIdx.x;
    if (i < NBUCK) gticket[i] = i * CAP;
}

// ---------------- coarse: bucket edges by dst>>8, single 8B packed store -----
__global__ __launch_bounds__(512) void coarse_k(
        const int* __restrict__ src, const int* __restrict__ dst,
        const float* __restrict__ val, int* __restrict__ gticket,
        int2* __restrict__ ev) {
    __shared__ int hist[NBUCK];
    __shared__ int base[NBUCK];
    __shared__ int tick[NBUCK];
    int t  = threadIdx.x;
    int lo = blockIdx.x * CHUNK;
    int hi = lo + CHUNK;           // NNZ divisible by NB_C
    for (int i = t; i < NBUCK; i += blockDim.x) hist[i] = 0;
    __syncthreads();
    for (int e = lo + t; e < hi; e += blockDim.x)
        atomicAdd(&hist[dst[e] >> 8], 1);
    __syncthreads();
    for (int i = t; i < NBUCK; i += blockDim.x) {
        base[i] = atomicAdd(&gticket[i], hist[i]);   // one agent atomic per (block,bucket)
        tick[i] = 0;
    }
    __syncthreads();
    for (int e = lo + t; e < hi; e += blockDim.x) {
        int d  = dst[e];
        int bk = d >> 8;
        int p  = base[bk] + atomicAdd(&tick[bk], 1); // LDS ticket
        ev[p]  = make_int2(src[e] | ((d & 255) << 18), __float_as_int(val[e]));
    }
}

// ---------------- scanC: bucket bases from final tickets ---------------------
__global__ void scanC_k(const int* __restrict__ gticket, int* __restrict__ bktbase) {
    __shared__ int sh[1024];
    int tid = threadIdx.x;
    int v = (tid < NBUCK) ? (gticket[tid] - tid * CAP) : 0;
    sh[tid] = v;
    __syncthreads();
    for (int off = 1; off < 1024; off <<= 1) {
        int t = (tid >= off) ? sh[tid - off] : 0;
        __syncthreads();
        sh[tid] += t;
        __syncthreads();
    }
    if (tid < NBUCK) bktbase[tid] = sh[tid] - v;   // exclusive
}

// ---------------- fine: per-bucket counting sort fully in LDS ----------------
__global__ void fine_k(const int* __restrict__ gticket, const int* __restrict__ bktbase,
                       const int2* __restrict__ ev,
                       int2* __restrict__ sorted, int* __restrict__ row) {
    __shared__ int hist[256];
    __shared__ int sh[256];
    int k = blockIdx.x, t = threadIdx.x;
    hist[t] = 0;
    __syncthreads();
    int cnt = gticket[k] - k * CAP;
    int s0  = k * CAP;
    for (int i = t; i < cnt; i += 256)
        atomicAdd(&hist[(ev[s0 + i].x >> 18) & 255], 1);
    __syncthreads();
    int v = hist[t];
    sh[t] = v;
    __syncthreads();
    for (int off = 1; off < 256; off <<= 1) {
        int tmp = (t >= off) ? sh[t - off] : 0;
        __syncthreads();
        sh[t] += tmp;
        __syncthreads();
    }
    int excl    = sh[t] - v;
    int rowbase = bktbase[k];
    int node    = (k << 8) + t;
    if (node < N_NODES) row[node] = rowbase + excl;
    if (k == 0 && t == 0) row[N_NODES] = NNZ;
    hist[t] = excl;                 // re-seed as ticket
    __syncthreads();
    for (int i = t; i < cnt; i += 256) {
        int2 r = ev[s0 + i];
        int p  = atomicAdd(&hist[(r.x >> 18) & 255], 1);   // LDS ticket = local pos
        sorted[rowbase + p] = make_int2(r.x & 0x3FFFF, r.y);
    }
}

// ---------------- conv: concat embeddings into X0 (fp16) ---------------------
__global__ void conv_k(const float4* __restrict__ ue, const float4* __restrict__ ie,
                       ushort4* __restrict__ X0) {
    int i = blockIdx.x * blockDim.x + threadIdx.x;
    const int total  = N_NODES * DIM / 4;
    const int ubound = N_USERS * DIM / 4;
    if (i >= total) return;
    float4 v = (i < ubound) ? ue[i] : ie[i - ubound];
    f16 a = __float2half(v.x), b = __float2half(v.y);
    f16 c = __float2half(v.z), d = __float2half(v.w);
    ushort4 o;
    o.x = *reinterpret_cast<ushort*>(&a);
    o.y = *reinterpret_cast<ushort*>(&b);
    o.z = *reinterpret_cast<ushort*>(&c);
    o.w = *reinterpret_cast<ushort*>(&d);
    X0[i] = o;
}

// ---------------- gather SpMM, 16 lanes per row (4 edges/wave-instr) ---------
// X4/Y4: rows as 16 x uint2 (4 f16 per lane). lane = 16*sub + quad,
// sub = edge subgroup, quad covers dims 4*quad..4*quad+3.
__global__ void gather16_k(const int* __restrict__ row, const int2* __restrict__ se,
                           const uint2* __restrict__ X4, uint2* __restrict__ Y4) {
    int wid  = (blockIdx.x * blockDim.x + threadIdx.x) >> 6;   // node
    int lane = threadIdx.x & 63;
    if (wid >= N_NODES) return;
    int sub  = lane >> 4;          // 0..3 : which edge of the group
    int quad = lane & 15;          // 0..15: which 8B of the row
    int beg = row[wid], end = row[wid + 1];
    float a0 = 0.f, a1 = 0.f, a2 = 0.f, a3 = 0.f;
    for (int base = beg; base < end; base += 64) {
        int rem = end - base;
        int n = rem < 64 ? rem : 64;
        int2 evv = make_int2(0, 0);
        if (lane < n) evv = se[base + lane];
        int ng = (n + 3) >> 2;                     // groups of 4 edges
        for (int g0 = 0; g0 < ng; g0 += 4) {
            uint2 xr[4]; float vs[4];
            #pragma unroll
            for (int k = 0; k < 4; ++k) {
                int ei = ((g0 + k) << 2) + sub;    // <=63; padded lanes are (0,0)
                int sx = __shfl(evv.x, ei, 64);
                vs[k]  = __int_as_float(__shfl(evv.y, ei, 64));
                xr[k]  = X4[((size_t)sx << 4) + quad];
            }
            #pragma unroll
            for (int k = 0; k < 4; ++k) {
                float2 f0 = __half22float2(*reinterpret_cast<const half2*>(&xr[k].x));
                float2 f1 = __half22float2(*reinterpret_cast<const half2*>(&xr[k].y));
                a0 += vs[k] * f0.x;
                a1 += vs[k] * f0.y;
                a2 += vs[k] * f1.x;
                a3 += vs[k] * f1.y;
            }
        }
    }
    // sum the 4 edge-subgroups (lanes l, l^16, l^32, l^48)
    a0 += __shfl_xor(a0, 16, 64);  a1 += __shfl_xor(a1, 16, 64);
    a2 += __shfl_xor(a2, 16, 64);  a3 += __shfl_xor(a3, 16, 64);
    a0 += __shfl_xor(a0, 32, 64);  a1 += __shfl_xor(a1, 32, 64);
    a2 += __shfl_xor(a2, 32, 64);  a3 += __shfl_xor(a3, 32, 64);
    if (sub == 0) {
        half2 h0 = __floats2half2_rn(a0, a1);
        half2 h1 = __floats2half2_rn(a2, a3);
        uint2 o;
        o.x = *reinterpret_cast<uint*>(&h0);
        o.y = *reinterpret_cast<uint*>(&h1);
        Y4[((size_t)wid << 4) + quad] = o;
    }
}

// ---------------- gather layer 3 for ONLY the batch's nodes ------------------
__global__ void gather3_k(const int* __restrict__ users, const int* __restrict__ items,
                          const int* __restrict__ row, const int2* __restrict__ se,
                          const f16* __restrict__ X, f16* __restrict__ X3p) {
    int s    = (blockIdx.x * blockDim.x + threadIdx.x) >> 6;   // slot
    int lane = threadIdx.x & 63;
    if (s >= 2 * BATCH) return;
    int wid = (s < BATCH) ? users[s] : (N_USERS + items[s - BATCH]);
    int beg = row[wid], end = row[wid + 1];
    float acc = 0.f;
    for (int base = beg; base < end; base += 64) {
        int rem = end - base;
        int n = rem < 64 ? rem : 64;
        int2 evv = make_int2(0, 0);
        if (lane < n) evv = se[base + lane];
        int n8 = (n + 7) & ~7;
        for (int j = 0; j < n8; j += 8) {
            float xv[8], vv[8];
            #pragma unroll
            for (int k = 0; k < 8; ++k) {
                int sr = __shfl(evv.x, j + k, 64);
                vv[k] = __int_as_float(__shfl(evv.y, j + k, 64));
                xv[k] = h2f(X[(sr << 6) + lane]);
            }
            #pragma unroll
            for (int k = 0; k < 8; ++k) acc += vv[k] * xv[k];
        }
    }
    X3p[(s << 6) + lane] = __float2half(acc);
}

// ---------------- final: acc = (e0+x1+x2+x3)/4 for gathered rows, dot, sigmoid
__global__ void final_k(const int* __restrict__ users, const int* __restrict__ items,
                        const float* __restrict__ ue, const float* __restrict__ ie,
                        const f16* __restrict__ X1, const f16* __restrict__ X2,
                        const f16* __restrict__ X3p, float* __restrict__ out) {
    int b    = blockIdx.x * (blockDim.x / 64) + (threadIdx.x / 64);
    int lane = threadIdx.x & 63;
    if (b >= BATCH) return;
    int u  = users[b];
    int it = items[b];
    int uo = (u << 6) + lane;
    int io = ((N_USERS + it) << 6) + lane;
    float au = ue[uo]               + h2f(X1[uo]) + h2f(X2[uo]) + h2f(X3p[(b << 6) + lane]);
    float ai = ie[(it << 6) + lane] + h2f(X1[io]) + h2f(X2[io]) + h2f(X3p[((b + BATCH) << 6) + lane]);
    float p = au * ai * (1.0f / 16.0f);
    #pragma unroll
    for (int off = 32; off; off >>= 1) p += __shfl_down(p, off, 64);
    if (lane == 0) out[b] = 1.0f / (1.0f + __expf(-p));
}

extern "C" void kernel_launch(void* const* d_in, const int* in_sizes, int n_in,
                              void* d_out, int out_size, void* d_ws, size_t ws_size,
                              hipStream_t stream) {
    const int*   users = (const int*)  d_in[0];
    const int*   items = (const int*)  d_in[1];
    const int*   esrc  = (const int*)  d_in[2];
    const int*   edst  = (const int*)  d_in[3];
    const float* eval  = (const float*)d_in[4];
    const float* uemb  = (const float*)d_in[5];
    const float* iemb  = (const float*)d_in[6];
    float*       out   = (float*)      d_out;

    const size_t XB = (size_t)N_NODES * DIM * sizeof(f16);         // 19.2 MB
    char* ws = (char*)d_ws;
    f16*  X0     = (f16*) (ws);
    f16*  X1     = (f16*) (ws + XB);
    f16*  X2     = (f16*) (ws + 2 * XB);
    f16*  X3p    = (f16*) (ws + 3 * XB);                           // 1 MB (2*BATCH rows)
    int2* sorted = (int2*)(ws + 3 * XB + ((size_t)2 * BATCH * DIM * 2 + 255 & ~255UL));
    char* p      = (char*)sorted + (size_t)NNZ * sizeof(int2);     // 32 MB
    int*  row     = (int*)(p);                 p += ((size_t)(N_NODES + 1) * 4 + 255) & ~255UL;
    int*  gticket = (int*)(p);                 p += (NBUCK * 4 + 255) & ~255UL;
    int*  bktbase = (int*)(p);
    // coarse staging aliases X0+X1 (dead until conv_k / gathers)
    int2* cev = (int2*)(ws);                                       // 32 MB

    // ---- CSR build: LDS counting sort, no fabric atomics on hot path ----
    initt_k<<<(NBUCK + 255) / 256, 256, 0, stream>>>(gticket);
    coarse_k<<<NB_C, 512, 0, stream>>>(esrc, edst, eval, gticket, cev);
    scanC_k<<<1, 1024, 0, stream>>>(gticket, bktbase);
    fine_k<<<NBUCK, 256, 0, stream>>>(gticket, bktbase, cev, sorted, row);

    // ---- X0 = concat(uemb, iemb) in fp16 (coarse staging now dead) ----
    conv_k<<<(N_NODES * DIM / 4 + 255) / 256, 256, 0, stream>>>(
        (const float4*)uemb, (const float4*)iemb, (ushort4*)X0);

    // ---- layers 1,2 full; layer 3 only for batch nodes ----
    const int gthreads = N_NODES * 64;
    gather16_k<<<(gthreads + 255) / 256, 256, 0, stream>>>(row, sorted,
                                                           (const uint2*)X0, (uint2*)X1);
    gather16_k<<<(gthreads + 255) / 256, 256, 0, stream>>>(row, sorted,
                                                           (const uint2*)X1, (uint2*)X2);
    gather3_k<<<(2 * BATCH * 64 + 255) / 256, 256, 0, stream>>>(users, items, row,
                                                                sorted, X2, X3p);

    final_k<<<(BATCH * 64 + 255) / 256, 256, 0, stream>>>(users, items, uemb, iemb,
                                                          X1, X2, X3p, out);
}

// Round 10
// 234.022 us; speedup vs baseline: 1.9114x; 1.0557x over previous
//
#include <hip/hip_runtime.h>
#include <hip/hip_fp16.h>

#define N_USERS 100000
#define N_ITEMS 50000
#define N_NODES 150000
#define DIM 64
#define NNZ 4000000
#define BATCH 4096

#define NBUCK 586          // ceil(150000/256) buckets of 256 nodes
#define CAP   7680         // bucket capacity: mean 6827, sigma 82.5 -> +10.3 sigma
#define NB_C  256          // coarse blocks (1 per CU)
#define CHUNK (NNZ / NB_C) // 15625 edges per block, sorted entirely in LDS

typedef __half f16;

__device__ __forceinline__ float h2f(f16 h) { return __half2float(h); }

// record: .x = src | (d&255)<<18   .y = val bits
// ---------------- gticket init: gticket[k] = k*CAP ---------------------------
__global__ void initt_k(int* __restrict__ gticket) {
    int i = blockIdx.x * blockDim.x + threadIdx.x;
    if (i < NBUCK) gticket[i] = i * CAP;
}

// ---------------- coarse: LDS counting sort of the chunk, coalesced write-out
// dynamic LDS: int2 buf[CHUNK] | int hist[NBUCK] | lbase | gbase | tick
__global__ __launch_bounds__(1024) void coarse_k(
        const int* __restrict__ src, const int* __restrict__ dst,
        const float* __restrict__ val, int* __restrict__ gticket,
        int2* __restrict__ ev) {
    extern __shared__ char smem[];
    int2* buf   = (int2*)smem;                       // CHUNK records (125000 B)
    int*  hist  = (int*)(smem + (size_t)CHUNK * 8);
    int*  lbase = hist  + NBUCK;
    int*  gbase = lbase + NBUCK;
    int*  tick  = gbase + NBUCK;
    const int t  = threadIdx.x;
    const int nt = blockDim.x;
    const int lo = blockIdx.x * CHUNK;
    const int hi = lo + CHUNK;                       // NNZ divisible by NB_C

    for (int i = t; i < NBUCK; i += nt) { hist[i] = 0; tick[i] = 0; }
    __syncthreads();
    // pass 1: histogram over 586 buckets
    for (int e = lo + t; e < hi; e += nt)
        atomicAdd(&hist[dst[e] >> 8], 1);
    __syncthreads();
    // wave 0: exclusive scan of hist -> lbase (586 = 10 chunks of 64)
    if (t < 64) {
        int lane = t;
        int carry = 0;
        for (int c = 0; c < (NBUCK + 63) / 64; ++c) {
            int idx = c * 64 + lane;
            int v = (idx < NBUCK) ? hist[idx] : 0;
            int s = v;
            #pragma unroll
            for (int off = 1; off < 64; off <<= 1) {
                int u = __shfl_up(s, off, 64);
                if (lane >= off) s += u;
            }
            if (idx < NBUCK) lbase[idx] = carry + s - v;
            carry += __shfl(s, 63, 64);
        }
    }
    // concurrently OK: gbase only needs hist
    for (int i = t; i < NBUCK; i += nt)
        gbase[i] = atomicAdd(&gticket[i], hist[i]);  // one agent atomic per (block,bucket)
    __syncthreads();
    // pass 2: scatter records into LDS (random LDS, cheap)
    for (int e = lo + t; e < hi; e += nt) {
        int d  = dst[e];
        int bk = d >> 8;
        int p  = lbase[bk] + atomicAdd(&tick[bk], 1);
        buf[p] = make_int2(src[e] | ((d & 255) << 18), __float_as_int(val[e]));
    }
    __syncthreads();
    // pass 3: per-wave bucket copy-out, contiguous global stores
    int wid = t >> 6, lane = t & 63, nw = nt >> 6;
    for (int bk = wid; bk < NBUCK; bk += nw) {
        int cnt = hist[bk], lb = lbase[bk], gb = gbase[bk];
        for (int i = lane; i < cnt; i += 64)
            ev[gb + i] = buf[lb + i];
    }
}

// ---------------- scanC: bucket bases from final tickets ---------------------
__global__ void scanC_k(const int* __restrict__ gticket, int* __restrict__ bktbase) {
    __shared__ int sh[1024];
    int tid = threadIdx.x;
    int v = (tid < NBUCK) ? (gticket[tid] - tid * CAP) : 0;
    sh[tid] = v;
    __syncthreads();
    for (int off = 1; off < 1024; off <<= 1) {
        int t = (tid >= off) ? sh[tid - off] : 0;
        __syncthreads();
        sh[tid] += t;
        __syncthreads();
    }
    if (tid < NBUCK) bktbase[tid] = sh[tid] - v;   // exclusive
}

// ---------------- fine: per-bucket counting sort fully in LDS ----------------
__global__ void fine_k(const int* __restrict__ gticket, const int* __restrict__ bktbase,
                       const int2* __restrict__ ev,
                       int2* __restrict__ sorted, int* __restrict__ row) {
    __shared__ int hist[256];
    __shared__ int sh[256];
    int k = blockIdx.x, t = threadIdx.x;
    hist[t] = 0;
    __syncthreads();
    int cnt = gticket[k] - k * CAP;
    int s0  = k * CAP;
    for (int i = t; i < cnt; i += 256)
        atomicAdd(&hist[(ev[s0 + i].x >> 18) & 255], 1);
    __syncthreads();
    int v = hist[t];
    sh[t] = v;
    __syncthreads();
    for (int off = 1; off < 256; off <<= 1) {
        int tmp = (t >= off) ? sh[t - off] : 0;
        __syncthreads();
        sh[t] += tmp;
        __syncthreads();
    }
    int excl    = sh[t] - v;
    int rowbase = bktbase[k];
    int node    = (k << 8) + t;
    if (node < N_NODES) row[node] = rowbase + excl;
    if (k == 0 && t == 0) row[N_NODES] = NNZ;
    hist[t] = excl;                 // re-seed as ticket
    __syncthreads();
    for (int i = t; i < cnt; i += 256) {
        int2 r = ev[s0 + i];
        int p  = atomicAdd(&hist[(r.x >> 18) & 255], 1);   // LDS ticket = local pos
        sorted[rowbase + p] = make_int2(r.x & 0x3FFFF, r.y);
    }
}

// ---------------- conv: concat embeddings into X0 (fp16) ---------------------
__global__ void conv_k(const float4* __restrict__ ue, const float4* __restrict__ ie,
                       ushort4* __restrict__ X0) {
    int i = blockIdx.x * blockDim.x + threadIdx.x;
    const int total  = N_NODES * DIM / 4;
    const int ubound = N_USERS * DIM / 4;
    if (i >= total) return;
    float4 v = (i < ubound) ? ue[i] : ie[i - ubound];
    f16 a = __float2half(v.x), b = __float2half(v.y);
    f16 c = __float2half(v.z), d = __float2half(v.w);
    ushort4 o;
    o.x = *reinterpret_cast<ushort*>(&a);
    o.y = *reinterpret_cast<ushort*>(&b);
    o.z = *reinterpret_cast<ushort*>(&c);
    o.w = *reinterpret_cast<ushort*>(&d);
    X0[i] = o;
}

// ---------------- gather SpMM, 16 lanes per row (4 edges/wave-instr) ---------
__global__ void gather16_k(const int* __restrict__ row, const int2* __restrict__ se,
                           const uint2* __restrict__ X4, uint2* __restrict__ Y4) {
    int wid  = (blockIdx.x * blockDim.x + threadIdx.x) >> 6;   // node
    int lane = threadIdx.x & 63;
    if (wid >= N_NODES) return;
    int sub  = lane >> 4;          // 0..3 : which edge of the group
    int quad = lane & 15;          // 0..15: which 8B of the row
    int beg = row[wid], end = row[wid + 1];
    float a0 = 0.f, a1 = 0.f, a2 = 0.f, a3 = 0.f;
    for (int base = beg; base < end; base += 64) {
        int rem = end - base;
        int n = rem < 64 ? rem : 64;
        int2 evv = make_int2(0, 0);
        if (lane < n) evv = se[base + lane];
        int ng = (n + 3) >> 2;                     // groups of 4 edges
        for (int g0 = 0; g0 < ng; g0 += 4) {
            uint2 xr[4]; float vs[4];
            #pragma unroll
            for (int k = 0; k < 4; ++k) {
                int ei = ((g0 + k) << 2) + sub;    // <=63; padded lanes are (0,0)
                int sx = __shfl(evv.x, ei, 64);
                vs[k]  = __int_as_float(__shfl(evv.y, ei, 64));
                xr[k]  = X4[((size_t)sx << 4) + quad];
            }
            #pragma unroll
            for (int k = 0; k < 4; ++k) {
                float2 f0 = __half22float2(*reinterpret_cast<const half2*>(&xr[k].x));
                float2 f1 = __half22float2(*reinterpret_cast<const half2*>(&xr[k].y));
                a0 += vs[k] * f0.x;
                a1 += vs[k] * f0.y;
                a2 += vs[k] * f1.x;
                a3 += vs[k] * f1.y;
            }
        }
    }
    a0 += __shfl_xor(a0, 16, 64);  a1 += __shfl_xor(a1, 16, 64);
    a2 += __shfl_xor(a2, 16, 64);  a3 += __shfl_xor(a3, 16, 64);
    a0 += __shfl_xor(a0, 32, 64);  a1 += __shfl_xor(a1, 32, 64);
    a2 += __shfl_xor(a2, 32, 64);  a3 += __shfl_xor(a3, 32, 64);
    if (sub == 0) {
        half2 h0 = __floats2half2_rn(a0, a1);
        half2 h1 = __floats2half2_rn(a2, a3);
        uint2 o;
        o.x = *reinterpret_cast<uint*>(&h0);
        o.y = *reinterpret_cast<uint*>(&h1);
        Y4[((size_t)wid << 4) + quad] = o;
    }
}

// ---------------- gather layer 3 for ONLY the batch's nodes ------------------
__global__ void gather3_k(const int* __restrict__ users, const int* __restrict__ items,
                          const int* __restrict__ row, const int2* __restrict__ se,
                          const f16* __restrict__ X, f16* __restrict__ X3p) {
    int s    = (blockIdx.x * blockDim.x + threadIdx.x) >> 6;   // slot
    int lane = threadIdx.x & 63;
    if (s >= 2 * BATCH) return;
    int wid = (s < BATCH) ? users[s] : (N_USERS + items[s - BATCH]);
    int beg = row[wid], end = row[wid + 1];
    float acc = 0.f;
    for (int base = beg; base < end; base += 64) {
        int rem = end - base;
        int n = rem < 64 ? rem : 64;
        int2 evv = make_int2(0, 0);
        if (lane < n) evv = se[base + lane];
        int n8 = (n + 7) & ~7;
        for (int j = 0; j < n8; j += 8) {
            float xv[8], vv[8];
            #pragma unroll
            for (int k = 0; k < 8; ++k) {
                int sr = __shfl(evv.x, j + k, 64);
                vv[k] = __int_as_float(__shfl(evv.y, j + k, 64));
                xv[k] = h2f(X[(sr << 6) + lane]);
            }
            #pragma unroll
            for (int k = 0; k < 8; ++k) acc += vv[k] * xv[k];
        }
    }
    X3p[(s << 6) + lane] = __float2half(acc);
}

// ---------------- final: acc = (e0+x1+x2+x3)/4 for gathered rows, dot, sigmoid
__global__ void final_k(const int* __restrict__ users, const int* __restrict__ items,
                        const float* __restrict__ ue, const float* __restrict__ ie,
                        const f16* __restrict__ X1, const f16* __restrict__ X2,
                        const f16* __restrict__ X3p, float* __restrict__ out) {
    int b    = blockIdx.x * (blockDim.x / 64) + (threadIdx.x / 64);
    int lane = threadIdx.x & 63;
    if (b >= BATCH) return;
    int u  = users[b];
    int it = items[b];
    int uo = (u << 6) + lane;
    int io = ((N_USERS + it) << 6) + lane;
    float au = ue[uo]               + h2f(X1[uo]) + h2f(X2[uo]) + h2f(X3p[(b << 6) + lane]);
    float ai = ie[(it << 6) + lane] + h2f(X1[io]) + h2f(X2[io]) + h2f(X3p[((b + BATCH) << 6) + lane]);
    float p = au * ai * (1.0f / 16.0f);
    #pragma unroll
    for (int off = 32; off; off >>= 1) p += __shfl_down(p, off, 64);
    if (lane == 0) out[b] = 1.0f / (1.0f + __expf(-p));
}

extern "C" void kernel_launch(void* const* d_in, const int* in_sizes, int n_in,
                              void* d_out, int out_size, void* d_ws, size_t ws_size,
                              hipStream_t stream) {
    const int*   users = (const int*)  d_in[0];
    const int*   items = (const int*)  d_in[1];
    const int*   esrc  = (const int*)  d_in[2];
    const int*   edst  = (const int*)  d_in[3];
    const float* eval  = (const float*)d_in[4];
    const float* uemb  = (const float*)d_in[5];
    const float* iemb  = (const float*)d_in[6];
    float*       out   = (float*)      d_out;

    const size_t XB = (size_t)N_NODES * DIM * sizeof(f16);         // 19.2 MB
    char* ws = (char*)d_ws;
    f16*  X0     = (f16*) (ws);
    f16*  X1     = (f16*) (ws + XB);
    f16*  X2     = (f16*) (ws + 2 * XB);
    f16*  X3p    = (f16*) (ws + 3 * XB);                           // 1 MB (2*BATCH rows)
    int2* sorted = (int2*)(ws + 3 * XB + ((size_t)2 * BATCH * DIM * 2 + 255 & ~255UL));
    char* p      = (char*)sorted + (size_t)NNZ * sizeof(int2);     // 32 MB
    int*  row     = (int*)(p);                 p += ((size_t)(N_NODES + 1) * 4 + 255) & ~255UL;
    int*  gticket = (int*)(p);                 p += (NBUCK * 4 + 255) & ~255UL;
    int*  bktbase = (int*)(p);
    // coarse staging aliases X0+X1 (dead until conv_k / gathers)
    int2* cev = (int2*)(ws);                                       // 32 MB

    // coarse needs 134 KB dynamic LDS (gfx950 allows 160 KB/workgroup)
    const size_t CLDS = (size_t)CHUNK * 8 + (size_t)4 * NBUCK * 4; // 134376 B
    hipFuncSetAttribute((const void*)coarse_k,
                        hipFuncAttributeMaxDynamicSharedMemorySize, (int)CLDS);

    // ---- CSR build: LDS counting sort, coalesced global writes ----
    initt_k<<<(NBUCK + 255) / 256, 256, 0, stream>>>(gticket);
    coarse_k<<<NB_C, 1024, CLDS, stream>>>(esrc, edst, eval, gticket, cev);
    scanC_k<<<1, 1024, 0, stream>>>(gticket, bktbase);
    fine_k<<<NBUCK, 256, 0, stream>>>(gticket, bktbase, cev, sorted, row);

    // ---- X0 = concat(uemb, iemb) in fp16 (coarse staging now dead) ----
    conv_k<<<(N_NODES * DIM / 4 + 255) / 256, 256, 0, stream>>>(
        (const float4*)uemb, (const float4*)iemb, (ushort4*)X0);

    // ---- layers 1,2 full; layer 3 only for batch nodes ----
    const int gthreads = N_NODES * 64;
    gather16_k<<<(gthreads + 255) / 256, 256, 0, stream>>>(row, sorted,
                                                           (const uint2*)X0, (uint2*)X1);
    gather16_k<<<(gthreads + 255) / 256, 256, 0, stream>>>(row, sorted,
                                                           (const uint2*)X1, (uint2*)X2);
    gather3_k<<<(2 * BATCH * 64 + 255) / 256, 256, 0, stream>>>(users, items, row,
                                                                sorted, X2, X3p);

    final_k<<<(BATCH * 64 + 255) / 256, 256, 0, stream>>>(users, items, uemb, iemb,
                                                          X1, X2, X3p, out);
}

// Round 11
// 226.862 us; speedup vs baseline: 1.9718x; 1.0316x over previous
//
#include <hip/hip_runtime.h>
#include <hip/hip_fp16.h>

#define N_USERS 100000
#define N_ITEMS 50000
#define N_NODES 150000
#define DIM 64
#define NNZ 4000000
#define BATCH 4096

#define NBUCK 586          // ceil(150000/256) buckets of 256 nodes
#define CAP   7680         // bucket capacity: mean 6827, sigma 82.5 -> +10.3 sigma
#define NB_C  250          // coarse blocks; CHUNK even for int2-vectorized loads
#define CHUNK (NNZ / NB_C) // 16000 edges per block, sorted entirely in LDS

typedef __half f16;

__device__ __forceinline__ float h2f(f16 h) { return __half2float(h); }

// record: .x = src | (d&255)<<18   .y = val bits
// ---------------- gticket init: gticket[k] = k*CAP ---------------------------
__global__ void initt_k(int* __restrict__ gticket) {
    int i = blockIdx.x * blockDim.x + threadIdx.x;
    if (i < NBUCK) gticket[i] = i * CAP;
}

// ---------------- coarse: LDS counting sort of the chunk, coalesced write-out
// dynamic LDS: int2 buf[CHUNK] | int hist[NBUCK] | lbase | gbase | tick
__global__ __launch_bounds__(1024) void coarse_k(
        const int* __restrict__ src, const int* __restrict__ dst,
        const float* __restrict__ val, int* __restrict__ gticket,
        int2* __restrict__ ev) {
    extern __shared__ char smem[];
    int2* buf   = (int2*)smem;                       // CHUNK records (128000 B)
    int*  hist  = (int*)(smem + (size_t)CHUNK * 8);
    int*  lbase = hist  + NBUCK;
    int*  gbase = lbase + NBUCK;
    int*  tick  = gbase + NBUCK;
    const int t  = threadIdx.x;
    const int nt = blockDim.x;
    const int lo = blockIdx.x * CHUNK;
    const int hi = lo + CHUNK;                       // NNZ divisible by NB_C

    for (int i = t; i < NBUCK; i += nt) { hist[i] = 0; tick[i] = 0; }
    __syncthreads();
    // pass 1: histogram over 586 buckets (2 edges / thread / iter)
    for (int e = lo + 2 * t; e < hi; e += 2 * nt) {
        int2 d2 = *reinterpret_cast<const int2*>(&dst[e]);
        atomicAdd(&hist[d2.x >> 8], 1);
        atomicAdd(&hist[d2.y >> 8], 1);
    }
    __syncthreads();
    // wave 0: exclusive scan of hist -> lbase (586 = 10 chunks of 64)
    if (t < 64) {
        int lane = t;
        int carry = 0;
        for (int c = 0; c < (NBUCK + 63) / 64; ++c) {
            int idx = c * 64 + lane;
            int v = (idx < NBUCK) ? hist[idx] : 0;
            int s = v;
            #pragma unroll
            for (int off = 1; off < 64; off <<= 1) {
                int u = __shfl_up(s, off, 64);
                if (lane >= off) s += u;
            }
            if (idx < NBUCK) lbase[idx] = carry + s - v;
            carry += __shfl(s, 63, 64);
        }
    }
    for (int i = t; i < NBUCK; i += nt)
        gbase[i] = atomicAdd(&gticket[i], hist[i]);  // one agent atomic per (block,bucket)
    __syncthreads();
    // pass 2: scatter records into LDS (vectorized reads, random LDS writes)
    for (int e = lo + 2 * t; e < hi; e += 2 * nt) {
        int2   d2 = *reinterpret_cast<const int2*>(&dst[e]);
        int2   s2 = *reinterpret_cast<const int2*>(&src[e]);
        float2 v2 = *reinterpret_cast<const float2*>(&val[e]);
        int bk0 = d2.x >> 8;
        int p0  = lbase[bk0] + atomicAdd(&tick[bk0], 1);
        buf[p0] = make_int2(s2.x | ((d2.x & 255) << 18), __float_as_int(v2.x));
        int bk1 = d2.y >> 8;
        int p1  = lbase[bk1] + atomicAdd(&tick[bk1], 1);
        buf[p1] = make_int2(s2.y | ((d2.y & 255) << 18), __float_as_int(v2.y));
    }
    __syncthreads();
    // pass 3: per-wave bucket copy-out, contiguous global stores
    int wid = t >> 6, lane = t & 63, nw = nt >> 6;
    for (int bk = wid; bk < NBUCK; bk += nw) {
        int cnt = hist[bk], lb = lbase[bk], gb = gbase[bk];
        for (int i = lane; i < cnt; i += 64)
            ev[gb + i] = buf[lb + i];
    }
}

// ---------------- scanC: bucket bases from final tickets ---------------------
__global__ void scanC_k(const int* __restrict__ gticket, int* __restrict__ bktbase) {
    __shared__ int sh[1024];
    int tid = threadIdx.x;
    int v = (tid < NBUCK) ? (gticket[tid] - tid * CAP) : 0;
    sh[tid] = v;
    __syncthreads();
    for (int off = 1; off < 1024; off <<= 1) {
        int t = (tid >= off) ? sh[tid - off] : 0;
        __syncthreads();
        sh[tid] += t;
        __syncthreads();
    }
    if (tid < NBUCK) bktbase[tid] = sh[tid] - v;   // exclusive
}

// ---------------- fine: per-bucket counting sort fully in LDS ----------------
__global__ void fine_k(const int* __restrict__ gticket, const int* __restrict__ bktbase,
                       const int2* __restrict__ ev,
                       int2* __restrict__ sorted, int* __restrict__ row) {
    __shared__ int hist[256];
    __shared__ int sh[256];
    int k = blockIdx.x, t = threadIdx.x;
    hist[t] = 0;
    __syncthreads();
    int cnt = gticket[k] - k * CAP;
    int s0  = k * CAP;
    for (int i = t; i < cnt; i += 256)
        atomicAdd(&hist[(ev[s0 + i].x >> 18) & 255], 1);
    __syncthreads();
    int v = hist[t];
    sh[t] = v;
    __syncthreads();
    for (int off = 1; off < 256; off <<= 1) {
        int tmp = (t >= off) ? sh[t - off] : 0;
        __syncthreads();
        sh[t] += tmp;
        __syncthreads();
    }
    int excl    = sh[t] - v;
    int rowbase = bktbase[k];
    int node    = (k << 8) + t;
    if (node < N_NODES) row[node] = rowbase + excl;
    if (k == 0 && t == 0) row[N_NODES] = NNZ;
    hist[t] = excl;                 // re-seed as ticket
    __syncthreads();
    for (int i = t; i < cnt; i += 256) {
        int2 r = ev[s0 + i];
        int p  = atomicAdd(&hist[(r.x >> 18) & 255], 1);   // LDS ticket = local pos
        sorted[rowbase + p] = make_int2(r.x & 0x3FFFF, r.y);
    }
}

// ---------------- conv: concat embeddings into X0 (fp16) ---------------------
__global__ void conv_k(const float4* __restrict__ ue, const float4* __restrict__ ie,
                       ushort4* __restrict__ X0) {
    int i = blockIdx.x * blockDim.x + threadIdx.x;
    const int total  = N_NODES * DIM / 4;
    const int ubound = N_USERS * DIM / 4;
    if (i >= total) return;
    float4 v = (i < ubound) ? ue[i] : ie[i - ubound];
    f16 a = __float2half(v.x), b = __float2half(v.y);
    f16 c = __float2half(v.z), d = __float2half(v.w);
    ushort4 o;
    o.x = *reinterpret_cast<ushort*>(&a);
    o.y = *reinterpret_cast<ushort*>(&b);
    o.z = *reinterpret_cast<ushort*>(&c);
    o.w = *reinterpret_cast<ushort*>(&d);
    X0[i] = o;
}

// ---------------- gather SpMM, 16 lanes per row, packed f16 FMA --------------
// Per-lane f16 acc chain only sums n/4 edges (its subgroup); cross-subgroup
// reduction done in f32 after one convert.
__global__ void gather16_k(const int* __restrict__ row, const int2* __restrict__ se,
                           const uint2* __restrict__ X4, uint2* __restrict__ Y4) {
    int wid  = (blockIdx.x * blockDim.x + threadIdx.x) >> 6;   // node
    int lane = threadIdx.x & 63;
    if (wid >= N_NODES) return;
    int sub  = lane >> 4;          // 0..3 : which edge of the group
    int quad = lane & 15;          // 0..15: which 8B of the row
    int beg = row[wid], end = row[wid + 1];
    half2 acc0 = __floats2half2_rn(0.f, 0.f);
    half2 acc1 = acc0;
    for (int base = beg; base < end; base += 64) {
        int rem = end - base;
        int n = rem < 64 ? rem : 64;
        int2 evv = make_int2(0, 0);
        if (lane < n) evv = se[base + lane];
        int ng = (n + 3) >> 2;                     // groups of 4 edges
        for (int g0 = 0; g0 < ng; g0 += 4) {
            uint2 xr[4]; float vs[4];
            #pragma unroll
            for (int k = 0; k < 4; ++k) {
                int ei = ((g0 + k) << 2) + sub;    // <=63; padded lanes are (0,0)
                int sx = __shfl(evv.x, ei, 64);
                vs[k]  = __int_as_float(__shfl(evv.y, ei, 64));
                xr[k]  = X4[((size_t)sx << 4) + quad];
            }
            #pragma unroll
            for (int k = 0; k < 4; ++k) {
                half2 vh = __float2half2_rn(vs[k]);
                acc0 = __hfma2(*reinterpret_cast<half2*>(&xr[k].x), vh, acc0);
                acc1 = __hfma2(*reinterpret_cast<half2*>(&xr[k].y), vh, acc1);
            }
        }
    }
    float2 f0 = __half22float2(acc0);
    float2 f1 = __half22float2(acc1);
    float a0 = f0.x, a1 = f0.y, a2 = f1.x, a3 = f1.y;
    a0 += __shfl_xor(a0, 16, 64);  a1 += __shfl_xor(a1, 16, 64);
    a2 += __shfl_xor(a2, 16, 64);  a3 += __shfl_xor(a3, 16, 64);
    a0 += __shfl_xor(a0, 32, 64);  a1 += __shfl_xor(a1, 32, 64);
    a2 += __shfl_xor(a2, 32, 64);  a3 += __shfl_xor(a3, 32, 64);
    if (sub == 0) {
        half2 h0 = __floats2half2_rn(a0, a1);
        half2 h1 = __floats2half2_rn(a2, a3);
        uint2 o;
        o.x = *reinterpret_cast<uint*>(&h0);
        o.y = *reinterpret_cast<uint*>(&h1);
        Y4[((size_t)wid << 4) + quad] = o;
    }
}

// ---------------- gather layer 3 for ONLY the batch's nodes (f32 acc) --------
__global__ void gather3_k(const int* __restrict__ users, const int* __restrict__ items,
                          const int* __restrict__ row, const int2* __restrict__ se,
                          const f16* __restrict__ X, f16* __restrict__ X3p) {
    int s    = (blockIdx.x * blockDim.x + threadIdx.x) >> 6;   // slot
    int lane = threadIdx.x & 63;
    if (s >= 2 * BATCH) return;
    int wid = (s < BATCH) ? users[s] : (N_USERS + items[s - BATCH]);
    int beg = row[wid], end = row[wid + 1];
    float acc = 0.f;
    for (int base = beg; base < end; base += 64) {
        int rem = end - base;
        int n = rem < 64 ? rem : 64;
        int2 evv = make_int2(0, 0);
        if (lane < n) evv = se[base + lane];
        int n8 = (n + 7) & ~7;
        for (int j = 0; j < n8; j += 8) {
            float xv[8], vv[8];
            #pragma unroll
            for (int k = 0; k < 8; ++k) {
                int sr = __shfl(evv.x, j + k, 64);
                vv[k] = __int_as_float(__shfl(evv.y, j + k, 64));
                xv[k] = h2f(X[(sr << 6) + lane]);
            }
            #pragma unroll
            for (int k = 0; k < 8; ++k) acc += vv[k] * xv[k];
        }
    }
    X3p[(s << 6) + lane] = __float2half(acc);
}

// ---------------- final: acc = (e0+x1+x2+x3)/4 for gathered rows, dot, sigmoid
__global__ void final_k(const int* __restrict__ users, const int* __restrict__ items,
                        const float* __restrict__ ue, const float* __restrict__ ie,
                        const f16* __restrict__ X1, const f16* __restrict__ X2,
                        const f16* __restrict__ X3p, float* __restrict__ out) {
    int b    = blockIdx.x * (blockDim.x / 64) + (threadIdx.x / 64);
    int lane = threadIdx.x & 63;
    if (b >= BATCH) return;
    int u  = users[b];
    int it = items[b];
    int uo = (u << 6) + lane;
    int io = ((N_USERS + it) << 6) + lane;
    float au = ue[uo]               + h2f(X1[uo]) + h2f(X2[uo]) + h2f(X3p[(b << 6) + lane]);
    float ai = ie[(it << 6) + lane] + h2f(X1[io]) + h2f(X2[io]) + h2f(X3p[((b + BATCH) << 6) + lane]);
    float p = au * ai * (1.0f / 16.0f);
    #pragma unroll
    for (int off = 32; off; off >>= 1) p += __shfl_down(p, off, 64);
    if (lane == 0) out[b] = 1.0f / (1.0f + __expf(-p));
}

extern "C" void kernel_launch(void* const* d_in, const int* in_sizes, int n_in,
                              void* d_out, int out_size, void* d_ws, size_t ws_size,
                              hipStream_t stream) {
    const int*   users = (const int*)  d_in[0];
    const int*   items = (const int*)  d_in[1];
    const int*   esrc  = (const int*)  d_in[2];
    const int*   edst  = (const int*)  d_in[3];
    const float* eval  = (const float*)d_in[4];
    const float* uemb  = (const float*)d_in[5];
    const float* iemb  = (const float*)d_in[6];
    float*       out   = (float*)      d_out;

    const size_t XB = (size_t)N_NODES * DIM * sizeof(f16);         // 19.2 MB
    char* ws = (char*)d_ws;
    f16*  X0     = (f16*) (ws);
    f16*  X1     = (f16*) (ws + XB);
    f16*  X2     = (f16*) (ws + 2 * XB);
    f16*  X3p    = (f16*) (ws + 3 * XB);                           // 1 MB (2*BATCH rows)
    int2* sorted = (int2*)(ws + 3 * XB + ((size_t)2 * BATCH * DIM * 2 + 255 & ~255UL));
    char* p      = (char*)sorted + (size_t)NNZ * sizeof(int2);     // 32 MB
    int*  row     = (int*)(p);                 p += ((size_t)(N_NODES + 1) * 4 + 255) & ~255UL;
    int*  gticket = (int*)(p);                 p += (NBUCK * 4 + 255) & ~255UL;
    int*  bktbase = (int*)(p);
    // coarse staging aliases X0+X1 (dead until conv_k / gathers)
    int2* cev = (int2*)(ws);                                       // 32 MB

    // coarse needs ~137 KB dynamic LDS (gfx950 allows 160 KB/workgroup)
    const size_t CLDS = (size_t)CHUNK * 8 + (size_t)4 * NBUCK * 4; // 137376 B
    hipFuncSetAttribute((const void*)coarse_k,
                        hipFuncAttributeMaxDynamicSharedMemorySize, (int)CLDS);

    // ---- CSR build: LDS counting sort, coalesced global writes ----
    initt_k<<<(NBUCK + 255) / 256, 256, 0, stream>>>(gticket);
    coarse_k<<<NB_C, 1024, CLDS, stream>>>(esrc, edst, eval, gticket, cev);
    scanC_k<<<1, 1024, 0, stream>>>(gticket, bktbase);
    fine_k<<<NBUCK, 256, 0, stream>>>(gticket, bktbase, cev, sorted, row);

    // ---- X0 = concat(uemb, iemb) in fp16 (coarse staging now dead) ----
    conv_k<<<(N_NODES * DIM / 4 + 255) / 256, 256, 0, stream>>>(
        (const float4*)uemb, (const float4*)iemb, (ushort4*)X0);

    // ---- layers 1,2 full; layer 3 only for batch nodes ----
    const int gthreads = N_NODES * 64;
    gather16_k<<<(gthreads + 255) / 256, 256, 0, stream>>>(row, sorted,
                                                           (const uint2*)X0, (uint2*)X1);
    gather16_k<<<(gthreads + 255) / 256, 256, 0, stream>>>(row, sorted,
                                                           (const uint2*)X1, (uint2*)X2);
    gather3_k<<<(2 * BATCH * 64 + 255) / 256, 256, 0, stream>>>(users, items, row,
                                                                sorted, X2, X3p);

    final_k<<<(BATCH * 64 + 255) / 256, 256, 0, stream>>>(users, items, uemb, iemb,
                                                          X1, X2, X3p, out);
}